// Round 12
// baseline (390.753 us; speedup 1.0000x reference)
//
#include <hip/hip_runtime.h>

#define NROWS 32768
#define DIM   128
#define KCODES 4096
#define DECAYF 0.8f
#define EPSF 1e-5f
#define COMMITW 0.25f

typedef _Float16 half8 __attribute__((ext_vector_type(8)));
typedef _Float16 half2v __attribute__((ext_vector_type(2)));
typedef float float16v __attribute__((ext_vector_type(16)));

// ---------------- embed -> staged split planes + e2 ----------------
// estg (halves): [chunk][slice][code6][8], slice = pl*16 + ks*2 + kh.
// Element (pl,ks,kh,c,j) = plane pl of e[c][ks*16 + kh*8 + j] -> exactly the
// 32x32x16 MFMA B-fragment order (n=lane&31, k=(lane>>5)*8+j).
__global__ __launch_bounds__(256) void esplit_kernel(const float* __restrict__ embed,
                                                     _Float16* __restrict__ estg,
                                                     float* __restrict__ e2h) {
    int code = blockIdx.x * 4 + (threadIdx.x >> 6);
    int lane = threadIdx.x & 63;
    float2 v = ((const float2*)(embed + (size_t)code * DIM))[lane];
    float s = v.x * v.x + v.y * v.y;
    #pragma unroll
    for (int off = 32; off > 0; off >>= 1) s += __shfl_down(s, off, 64);
    if (lane == 0) e2h[code] = 0.5f * s;

    int d = lane * 2;
    int ks = d >> 4, kh = (d >> 3) & 1, j = d & 7;
    _Float16 h0 = (_Float16)v.x, l0 = (_Float16)(v.x - (float)h0);
    _Float16 h1 = (_Float16)v.y, l1 = (_Float16)(v.y - (float)h1);
    int chunk = code >> 6, c6 = code & 63;
    size_t base = (size_t)chunk * 16384;
    size_t hidx = base + (size_t)(( 0 + ks * 2 + kh) * 64 + c6) * 8 + j;
    size_t lidx = base + (size_t)((16 + ks * 2 + kh) * 64 + c6) * 8 + j;
    *(half2v*)&estg[hidx] = (half2v){h0, h1};
    *(half2v*)&estg[lidx] = (half2v){l0, l1};
}

// ---------------- MFMA argmax: 32x32x16, 128 rows/block ----------------
// score = x.e - 0.5|e|^2 (folded into acc init). fp16 2-way split, 3 products.
// 512 thr / 8 waves: wave w -> code-tile ct=w&1 (32 codes), row-tile rt=w>>1
// (32 rows). A frags (8 ks x 2 planes, 64 VGPR) resident; B register dbuf.
// Barrier-free K-loop. C layout: col=lane&31, row=(reg&3)+8*(reg>>2)+4*(lane>>5).
// Hi-plane slice offset = ks*1024 (+kh*512 in bbase); LO-PLANE = 8192 + ks*1024
// (R11 bug was 16384+: read next chunk's hi plane).
__global__ __launch_bounds__(512, 2) void argmax_kernel(const float* __restrict__ x,
                                                        const _Float16* __restrict__ estg,
                                                        const float* __restrict__ e2h,
                                                        int* __restrict__ ind,
                                                        float* __restrict__ out_ind,
                                                        int* __restrict__ bins,
                                                        float* __restrict__ loss) {
    __shared__ float rv[2][128];
    __shared__ int   ri[2][128];
    __shared__ float x2s[128];

    int tid = threadIdx.x;
    int lane = tid & 63;
    int w = tid >> 6;
    int ct = w & 1;
    int rt = w >> 1;
    int n31 = lane & 31;
    int kh = lane >> 5;
    int n0 = blockIdx.x * 128;

    // A frags: row = n0 + rt*32 + n31; element k = ks*16 + kh*8 + j
    half8 Ah[8], Al[8];
    float xsq = 0.f;
    {
        const float* xr = x + (size_t)(n0 + rt * 32 + n31) * DIM + kh * 8;
        #pragma unroll
        for (int ks = 0; ks < 8; ++ks) {
            float4 a = *(const float4*)(xr + ks * 16);
            float4 b = *(const float4*)(xr + ks * 16 + 4);
            float f[8] = {a.x, a.y, a.z, a.w, b.x, b.y, b.z, b.w};
            half8 H, L;
            #pragma unroll
            for (int e = 0; e < 8; ++e) {
                _Float16 h = (_Float16)f[e];
                H[e] = h;
                L[e] = (_Float16)(f[e] - (float)h);
                xsq += f[e] * f[e];
            }
            Ah[ks] = H;
            Al[ks] = L;
        }
        xsq += __shfl_xor(xsq, 32, 64);   // combine the two k-halves
        if (ct == 0 && kh == 0) x2s[rt * 32 + n31] = xsq;
    }

    float best[16];
    int   bidx[16];
    #pragma unroll
    for (int r = 0; r < 16; ++r) { best[r] = -3.0e38f; bidx[r] = 0; }

    // B fragment lane base (halves): slice = pl*16 + ks*2 + kh;
    // addr = (slice*64 + ct*32 + n31)*8
    const _Float16* bbase = estg + (size_t)(kh * 64 + ct * 32 + n31) * 8;
    const int cm = ct * 32 + n31;     // code column for this lane

    half8 B0h[8], B0l[8], B1h[8], B1l[8];
    float e20, e21;

    {
        const _Float16* cb = bbase;
        #pragma unroll
        for (int ks = 0; ks < 8; ++ks) {
            B0h[ks] = *(const half8*)(cb + (size_t)ks * 1024);
            B0l[ks] = *(const half8*)(cb + 8192 + (size_t)ks * 1024);
        }
        e20 = e2h[cm];
    }

    #pragma unroll 1
    for (int ch = 0; ch < 64; ch += 2) {
        // prefetch ch+1 -> buf1
        {
            const _Float16* cb = bbase + (size_t)(ch + 1) * 16384;
            #pragma unroll
            for (int ks = 0; ks < 8; ++ks) {
                B1h[ks] = *(const half8*)(cb + (size_t)ks * 1024);
                B1l[ks] = *(const half8*)(cb + 8192 + (size_t)ks * 1024);
            }
            e21 = e2h[(ch + 1) * 64 + cm];
        }
        // compute ch from buf0
        {
            float16v acc;
            #pragma unroll
            for (int r = 0; r < 16; ++r) acc[r] = -e20;
            #pragma unroll
            for (int ks = 0; ks < 8; ++ks) {
                acc = __builtin_amdgcn_mfma_f32_32x32x16_f16(Ah[ks], B0h[ks], acc, 0, 0, 0);
                acc = __builtin_amdgcn_mfma_f32_32x32x16_f16(Al[ks], B0h[ks], acc, 0, 0, 0);
                acc = __builtin_amdgcn_mfma_f32_32x32x16_f16(Ah[ks], B0l[ks], acc, 0, 0, 0);
            }
            int c = ch * 64 + cm;
            #pragma unroll
            for (int r = 0; r < 16; ++r)
                if (acc[r] > best[r]) { best[r] = acc[r]; bidx[r] = c; }
        }
        // prefetch ch+2 -> buf0
        if (ch + 2 < 64) {
            const _Float16* cb = bbase + (size_t)(ch + 2) * 16384;
            #pragma unroll
            for (int ks = 0; ks < 8; ++ks) {
                B0h[ks] = *(const half8*)(cb + (size_t)ks * 1024);
                B0l[ks] = *(const half8*)(cb + 8192 + (size_t)ks * 1024);
            }
            e20 = e2h[(ch + 2) * 64 + cm];
        }
        // compute ch+1 from buf1
        {
            float16v acc;
            #pragma unroll
            for (int r = 0; r < 16; ++r) acc[r] = -e21;
            #pragma unroll
            for (int ks = 0; ks < 8; ++ks) {
                acc = __builtin_amdgcn_mfma_f32_32x32x16_f16(Ah[ks], B1h[ks], acc, 0, 0, 0);
                acc = __builtin_amdgcn_mfma_f32_32x32x16_f16(Al[ks], B1h[ks], acc, 0, 0, 0);
                acc = __builtin_amdgcn_mfma_f32_32x32x16_f16(Ah[ks], B1l[ks], acc, 0, 0, 0);
            }
            int c = (ch + 1) * 64 + cm;
            #pragma unroll
            for (int r = 0; r < 16; ++r)
                if (acc[r] > best[r]) { best[r] = acc[r]; bidx[r] = c; }
        }
    }

    // reduce across the 32 code columns (within each 32-lane half)
    #pragma unroll
    for (int r = 0; r < 16; ++r) {
        float bv = best[r];
        int   bi = bidx[r];
        #pragma unroll
        for (int m = 1; m <= 16; m <<= 1) {
            float ov = __shfl_xor(bv, m, 64);
            int   oi = __shfl_xor(bi, m, 64);
            if (ov > bv || (ov == bv && oi < bi)) { bv = ov; bi = oi; }
        }
        if (n31 == 0) {
            int row = rt * 32 + (r & 3) + 8 * (r >> 2) + 4 * kh;
            rv[ct][row] = bv;
            ri[ct][row] = bi;
        }
    }
    __syncthreads();
    if (tid < 128) {
        float bv = rv[0][tid];
        int   bi = ri[0][tid];
        float ov = rv[1][tid];
        int   oi = ri[1][tid];
        if (ov > bv || (ov == bv && oi < bi)) { bv = ov; bi = oi; }
        ind[n0 + tid] = bi;
        out_ind[n0 + tid] = (float)bi;
        atomicAdd(&bins[bi], 1);
        float lp = x2s[tid] - 2.0f * bv;   // |x-e|^2 = |x|^2 - 2*score
        #pragma unroll
        for (int off = 32; off > 0; off >>= 1) lp += __shfl_down(lp, off, 64);
        if ((tid & 63) == 0) atomicAdd(loss, lp);
    }
}

// ---------------- scan: offsets/cursor + out_cs + ntot + loss + empties ----
__global__ __launch_bounds__(1024) void scan_kernel(const int* __restrict__ bins,
                                                    const float* __restrict__ cluster_size,
                                                    const float* __restrict__ loss,
                                                    const float* __restrict__ embed_avg,
                                                    int* __restrict__ offsets,
                                                    int* __restrict__ cursor,
                                                    float* __restrict__ out_cs,
                                                    float* __restrict__ ntot,
                                                    float* __restrict__ out_loss,
                                                    float* __restrict__ out_norm) {
    __shared__ int   wtot[16];
    __shared__ float fred[16];
    __shared__ float stot;
    int t = threadIdx.x;
    int lane = t & 63, wv = t >> 6;
    int b[4];
    float cs[4];
    float csum = 0.f;
    int s = 0;
    #pragma unroll
    for (int e = 0; e < 4; ++e) {
        b[e] = bins[t * 4 + e];
        s += b[e];
        cs[e] = cluster_size[t * 4 + e] * DECAYF + (1.0f - DECAYF) * (float)b[e];
        csum += cs[e];
    }
    int sc = s;
    #pragma unroll
    for (int off = 1; off < 64; off <<= 1) {
        int v = __shfl_up(sc, off, 64);
        if (lane >= off) sc += v;
    }
    float fc = csum;
    #pragma unroll
    for (int off = 32; off > 0; off >>= 1) fc += __shfl_down(fc, off, 64);
    if (lane == 63) wtot[wv] = sc;
    if (lane == 0) fred[wv] = fc;
    __syncthreads();
    if (t < 16) {
        int v = wtot[t];
        int scv = v;
        #pragma unroll
        for (int off = 1; off < 16; off <<= 1) {
            int u = __shfl_up(scv, off, 64);
            if (t >= off) scv += u;
        }
        wtot[t] = scv - v;
    }
    if (t == 0) {
        float tot = 0.f;
        #pragma unroll
        for (int i = 0; i < 16; ++i) tot += fred[i];
        stot = tot;
        *ntot = tot;
        *out_loss = COMMITW * (*loss) / (float)((size_t)NROWS * DIM);
    }
    __syncthreads();
    float nt = stot;
    int ex = sc - s + wtot[wv];
    #pragma unroll
    for (int e = 0; e < 4; ++e) {
        int k = t * 4 + e;
        offsets[k] = ex;
        cursor[k] = ex;
        out_cs[k] = cs[e];
        ex += b[e];
        if (b[e] == 0) {   // empty code: esum = 0, finish out_norm here
            float cluster = (cs[e] + EPSF) / (nt + (float)KCODES * EPSF) * nt;
            float coef = DECAYF / cluster;
            float4* dst = (float4*)(out_norm + (size_t)k * DIM);
            const float4* ea = (const float4*)(embed_avg + (size_t)k * DIM);
            for (int i = 0; i < DIM / 4; ++i) {
                float4 v = ea[i];
                v.x *= coef; v.y *= coef; v.z *= coef; v.w *= coef;
                dst[i] = v;
            }
        }
    }
}

// ---------------- reorder rows by code (also emit sorted code list) --------
__global__ __launch_bounds__(256) void reorder_kernel(const int* __restrict__ ind,
                                                      int* __restrict__ cursor,
                                                      int* __restrict__ rowids,
                                                      int* __restrict__ codesorted) {
    int row = blockIdx.x * 256 + threadIdx.x;
    int k = ind[row];
    int pos = atomicAdd(&cursor[k], 1);
    rowids[pos] = row;
    codesorted[pos] = k;
}

// ---------------- segred + out_q + fused norm ----------------
// One wave per 16-row window of the sorted rows. Interior segments write
// out_norm directly; window-crossing segments atomicAdd esum + done-counter,
// last-arriving wave finalizes (device-scope atomics + threadfence).
#define WROWS 16
__global__ __launch_bounds__(256) void segred_kernel(const float* __restrict__ x,
                                                     const float* __restrict__ embed,
                                                     const int* __restrict__ rowids,
                                                     const int* __restrict__ codesorted,
                                                     const int* __restrict__ offsets,
                                                     const int* __restrict__ bins,
                                                     const float* __restrict__ embed_avg,
                                                     const float* __restrict__ out_cs,
                                                     const float* __restrict__ ntot,
                                                     float* __restrict__ esum,
                                                     int* __restrict__ done,
                                                     float* __restrict__ out_q,
                                                     float* __restrict__ out_norm) {
    int tid = threadIdx.x;
    int lane = tid & 63;
    int wv = blockIdx.x * 4 + (tid >> 6);
    int w0 = wv * WROWS;
    float nt = *ntot;

    int i16 = lane & (WROWS - 1);
    int rowv = rowids[w0 + i16];
    int kv   = codesorted[w0 + i16];

    float2 xv[WROWS];
    #pragma unroll
    for (int i = 0; i < WROWS; ++i) {
        int row = __shfl(rowv, i, 64);
        xv[i] = ((const float2*)(x + (size_t)row * DIM))[lane];
    }

    int curk = __shfl(kv, 0, 64);
    int runstart = 0;
    float2 qv = ((const float2*)(embed + (size_t)curk * DIM))[lane];
    float2 acc = {0.f, 0.f};

    #pragma unroll
    for (int i = 0; i <= WROWS; ++i) {
        int row = 0, k = 0;
        if (i < WROWS) {
            row = __shfl(rowv, i, 64);
            k   = __shfl(kv, i, 64);
        }
        if (i == WROWS || k != curk) {   // flush run [runstart, i) of code curk
            int sbeg = offsets[curk];
            int cnt  = bins[curk];
            float cs = out_cs[curk];
            float cluster = (cs + EPSF) / (nt + (float)KCODES * EPSF) * nt;
            float inv = 1.0f / cluster;
            size_t idx = (size_t)curk * DIM + lane * 2;
            if (sbeg >= w0 && sbeg + cnt <= w0 + WROWS) {
                float2 ea = *(const float2*)(embed_avg + idx);
                float2 o;
                o.x = (ea.x * DECAYF + (1.0f - DECAYF) * acc.x) * inv;
                o.y = (ea.y * DECAYF + (1.0f - DECAYF) * acc.y) * inv;
                *(float2*)(out_norm + idx) = o;
            } else {
                float* ep = esum + idx;
                atomicAdd(ep, acc.x);
                atomicAdd(ep + 1, acc.y);
                __threadfence();
                int rl = i - runstart;
                int old = 0;
                if (lane == 0) old = atomicAdd(&done[curk], rl);
                old = __shfl(old, 0, 64);
                if (old + rl == cnt) {
                    __threadfence();
                    float ex0 = atomicAdd(ep, 0.0f);       // coherent read
                    float ex1 = atomicAdd(ep + 1, 0.0f);
                    float2 ea = *(const float2*)(embed_avg + idx);
                    float2 o;
                    o.x = (ea.x * DECAYF + (1.0f - DECAYF) * ex0) * inv;
                    o.y = (ea.y * DECAYF + (1.0f - DECAYF) * ex1) * inv;
                    *(float2*)(out_norm + idx) = o;
                }
            }
            if (i == WROWS) break;
            curk = k;
            runstart = i;
            acc = (float2){0.f, 0.f};
            qv = ((const float2*)(embed + (size_t)curk * DIM))[lane];
        }
        acc.x += xv[i].x;
        acc.y += xv[i].y;
        ((float2*)(out_q + (size_t)row * DIM))[lane] = qv;
    }
}

extern "C" void kernel_launch(void* const* d_in, const int* in_sizes, int n_in,
                              void* d_out, int out_size, void* d_ws, size_t ws_size,
                              hipStream_t stream) {
    const float* x            = (const float*)d_in[0];
    const float* embed        = (const float*)d_in[1];
    const float* cluster_size = (const float*)d_in[2];
    const float* embed_avg    = (const float*)d_in[3];

    float* out      = (float*)d_out;
    float* out_q    = out;                               // 4194304
    float* out_ind  = out + 4194304;                     // 32768
    float* out_loss = out_ind + 32768;                   // 1
    float* out_cs   = out_loss + 1;                      // 4096
    float* out_norm = out_cs + 4096;                     // 524288

    // workspace layout (bytes)
    char* ws = (char*)d_ws;
    _Float16* estg = (_Float16*)ws;                      // 2,097,152
    float* e2h   = (float*)(ws + 2097152);               // 16,384
    int*   ind   = (int*)(ws + 2113536);                 // 131,072
    int*   offsets = (int*)(ws + 2244608);               // 16,384
    int*   cursor  = (int*)(ws + 2260992);               // 16,384
    int*   rowids  = (int*)(ws + 2277376);               // 131,072
    int*   codesorted = (int*)(ws + 2408448);            // 131,072
    float* loss  = (float*)(ws + 2539520);               // 4 (pad to 256)
    float* ntot  = loss + 1;
    int*   bins  = (int*)(ws + 2539776);                 // 16,384
    int*   done  = (int*)(ws + 2556160);                 // 16,384
    float* esum  = (float*)(ws + 2572544);               // 2,097,152

    // zero loss/pad + bins + done + esum (contiguous)
    hipMemsetAsync(ws + 2539520, 0, 256 + 16384 + 16384 + 2097152, stream);

    esplit_kernel<<<KCODES / 4, 256, 0, stream>>>(embed, estg, e2h);
    argmax_kernel<<<NROWS / 128, 512, 0, stream>>>(x, estg, e2h, ind, out_ind,
                                                   bins, loss);
    scan_kernel<<<1, 1024, 0, stream>>>(bins, cluster_size, loss, embed_avg,
                                        offsets, cursor, out_cs, ntot, out_loss,
                                        out_norm);
    reorder_kernel<<<NROWS / 256, 256, 0, stream>>>(ind, cursor, rowids, codesorted);
    segred_kernel<<<NROWS / WROWS / 4, 256, 0, stream>>>(x, embed, rowids, codesorted,
                                                         offsets, bins, embed_avg,
                                                         out_cs, ntot, esum, done,
                                                         out_q, out_norm);
}

// Round 13
// 328.363 us; speedup vs baseline: 1.1900x; 1.1900x over previous
//
#include <hip/hip_runtime.h>

#define NROWS 32768
#define DIM   128
#define KCODES 4096
#define DECAYF 0.8f
#define EPSF 1e-5f
#define COMMITW 0.25f

typedef _Float16 half8 __attribute__((ext_vector_type(8)));
typedef _Float16 half2v __attribute__((ext_vector_type(2)));
typedef float float16v __attribute__((ext_vector_type(16)));

// ---------------- embed -> staged split planes + e2 ----------------
// estg (halves): [chunk][slice][code6][8], slice = pl*16 + ks*2 + kh.
// Exactly the 32x32x16 MFMA B-fragment order (n=lane&31, k=(lane>>5)*8+j).
// Verified correct in R12 (passed).
__global__ __launch_bounds__(256) void esplit_kernel(const float* __restrict__ embed,
                                                     _Float16* __restrict__ estg,
                                                     float* __restrict__ e2h) {
    int code = blockIdx.x * 4 + (threadIdx.x >> 6);
    int lane = threadIdx.x & 63;
    float2 v = ((const float2*)(embed + (size_t)code * DIM))[lane];
    float s = v.x * v.x + v.y * v.y;
    #pragma unroll
    for (int off = 32; off > 0; off >>= 1) s += __shfl_down(s, off, 64);
    if (lane == 0) e2h[code] = 0.5f * s;

    int d = lane * 2;
    int ks = d >> 4, kh = (d >> 3) & 1, j = d & 7;
    _Float16 h0 = (_Float16)v.x, l0 = (_Float16)(v.x - (float)h0);
    _Float16 h1 = (_Float16)v.y, l1 = (_Float16)(v.y - (float)h1);
    int chunk = code >> 6, c6 = code & 63;
    size_t base = (size_t)chunk * 16384;
    size_t hidx = base + (size_t)(( 0 + ks * 2 + kh) * 64 + c6) * 8 + j;
    size_t lidx = base + (size_t)((16 + ks * 2 + kh) * 64 + c6) * 8 + j;
    *(half2v*)&estg[hidx] = (half2v){h0, h1};
    *(half2v*)&estg[lidx] = (half2v){l0, l1};
}

// ---------------- MFMA argmax: 32x32x16, 3 independent acc chains ----------
// score = x.e - 0.5|e|^2. fp16 2-way split, products hh/lh/hl accumulated in
// SEPARATE chains (round-robin issue -> depth-3 spacing hides MFMA latency;
// R12's single chain stalled at result latency, MfmaUtil 31%). Merged with
// 2 VALU adds per C element at compare time. Barrier-free K-loop, reg dbuf.
__global__ __launch_bounds__(512, 2) void argmax_kernel(const float* __restrict__ x,
                                                        const _Float16* __restrict__ estg,
                                                        const float* __restrict__ e2h,
                                                        int* __restrict__ ind,
                                                        float* __restrict__ out_ind,
                                                        int* __restrict__ bins,
                                                        float* __restrict__ loss) {
    __shared__ float rv[2][128];
    __shared__ int   ri[2][128];
    __shared__ float x2s[128];

    int tid = threadIdx.x;
    int lane = tid & 63;
    int w = tid >> 6;
    int ct = w & 1;
    int rt = w >> 1;
    int n31 = lane & 31;
    int kh = lane >> 5;
    int n0 = blockIdx.x * 128;

    // A frags: row = n0 + rt*32 + n31; element k = ks*16 + kh*8 + j
    half8 Ah[8], Al[8];
    float xsq = 0.f;
    {
        const float* xr = x + (size_t)(n0 + rt * 32 + n31) * DIM + kh * 8;
        #pragma unroll
        for (int ks = 0; ks < 8; ++ks) {
            float4 a = *(const float4*)(xr + ks * 16);
            float4 b = *(const float4*)(xr + ks * 16 + 4);
            float f[8] = {a.x, a.y, a.z, a.w, b.x, b.y, b.z, b.w};
            half8 H, L;
            #pragma unroll
            for (int e = 0; e < 8; ++e) {
                _Float16 h = (_Float16)f[e];
                H[e] = h;
                L[e] = (_Float16)(f[e] - (float)h);
                xsq += f[e] * f[e];
            }
            Ah[ks] = H;
            Al[ks] = L;
        }
        xsq += __shfl_xor(xsq, 32, 64);
        if (ct == 0 && kh == 0) x2s[rt * 32 + n31] = xsq;
    }

    float best[16];
    int   bidx[16];
    #pragma unroll
    for (int r = 0; r < 16; ++r) { best[r] = -3.0e38f; bidx[r] = 0; }

    // B fragment lane base (halves): slice = pl*16 + ks*2 + kh
    const _Float16* bbase = estg + (size_t)(kh * 64 + ct * 32 + n31) * 8;
    const int cm = ct * 32 + n31;

    half8 B0h[8], B0l[8], B1h[8], B1l[8];
    float e20, e21;

    {
        const _Float16* cb = bbase;
        #pragma unroll
        for (int ks = 0; ks < 8; ++ks) {
            B0h[ks] = *(const half8*)(cb + (size_t)ks * 1024);
            B0l[ks] = *(const half8*)(cb + 8192 + (size_t)ks * 1024);
        }
        e20 = e2h[cm];
    }

    #pragma unroll 1
    for (int ch = 0; ch < 64; ch += 2) {
        // prefetch ch+1 -> buf1
        {
            const _Float16* cb = bbase + (size_t)(ch + 1) * 16384;
            #pragma unroll
            for (int ks = 0; ks < 8; ++ks) {
                B1h[ks] = *(const half8*)(cb + (size_t)ks * 1024);
                B1l[ks] = *(const half8*)(cb + 8192 + (size_t)ks * 1024);
            }
            e21 = e2h[(ch + 1) * 64 + cm];
        }
        // compute ch from buf0 — 3 independent chains
        {
            float16v aHH, aLH, aHL;
            #pragma unroll
            for (int r = 0; r < 16; ++r) { aHH[r] = -e20; aLH[r] = 0.f; aHL[r] = 0.f; }
            #pragma unroll
            for (int ks = 0; ks < 8; ++ks) {
                aHH = __builtin_amdgcn_mfma_f32_32x32x16_f16(Ah[ks], B0h[ks], aHH, 0, 0, 0);
                aLH = __builtin_amdgcn_mfma_f32_32x32x16_f16(Al[ks], B0h[ks], aLH, 0, 0, 0);
                aHL = __builtin_amdgcn_mfma_f32_32x32x16_f16(Ah[ks], B0l[ks], aHL, 0, 0, 0);
            }
            int c = ch * 64 + cm;
            #pragma unroll
            for (int r = 0; r < 16; ++r) {
                float s = (aHH[r] + aLH[r]) + aHL[r];
                if (s > best[r]) { best[r] = s; bidx[r] = c; }
            }
        }
        // prefetch ch+2 -> buf0
        if (ch + 2 < 64) {
            const _Float16* cb = bbase + (size_t)(ch + 2) * 16384;
            #pragma unroll
            for (int ks = 0; ks < 8; ++ks) {
                B0h[ks] = *(const half8*)(cb + (size_t)ks * 1024);
                B0l[ks] = *(const half8*)(cb + 8192 + (size_t)ks * 1024);
            }
            e20 = e2h[(ch + 2) * 64 + cm];
        }
        // compute ch+1 from buf1
        {
            float16v aHH, aLH, aHL;
            #pragma unroll
            for (int r = 0; r < 16; ++r) { aHH[r] = -e21; aLH[r] = 0.f; aHL[r] = 0.f; }
            #pragma unroll
            for (int ks = 0; ks < 8; ++ks) {
                aHH = __builtin_amdgcn_mfma_f32_32x32x16_f16(Ah[ks], B1h[ks], aHH, 0, 0, 0);
                aLH = __builtin_amdgcn_mfma_f32_32x32x16_f16(Al[ks], B1h[ks], aLH, 0, 0, 0);
                aHL = __builtin_amdgcn_mfma_f32_32x32x16_f16(Ah[ks], B1l[ks], aHL, 0, 0, 0);
            }
            int c = (ch + 1) * 64 + cm;
            #pragma unroll
            for (int r = 0; r < 16; ++r) {
                float s = (aHH[r] + aLH[r]) + aHL[r];
                if (s > best[r]) { best[r] = s; bidx[r] = c; }
            }
        }
    }

    // reduce across the 32 code columns (within each 32-lane half)
    #pragma unroll
    for (int r = 0; r < 16; ++r) {
        float bv = best[r];
        int   bi = bidx[r];
        #pragma unroll
        for (int m = 1; m <= 16; m <<= 1) {
            float ov = __shfl_xor(bv, m, 64);
            int   oi = __shfl_xor(bi, m, 64);
            if (ov > bv || (ov == bv && oi < bi)) { bv = ov; bi = oi; }
        }
        if (n31 == 0) {
            int row = rt * 32 + (r & 3) + 8 * (r >> 2) + 4 * kh;
            rv[ct][row] = bv;
            ri[ct][row] = bi;
        }
    }
    __syncthreads();
    if (tid < 128) {
        float bv = rv[0][tid];
        int   bi = ri[0][tid];
        float ov = rv[1][tid];
        int   oi = ri[1][tid];
        if (ov > bv || (ov == bv && oi < bi)) { bv = ov; bi = oi; }
        ind[n0 + tid] = bi;
        out_ind[n0 + tid] = (float)bi;
        atomicAdd(&bins[bi], 1);
        float lp = x2s[tid] - 2.0f * bv;
        #pragma unroll
        for (int off = 32; off > 0; off >>= 1) lp += __shfl_down(lp, off, 64);
        if ((tid & 63) == 0) atomicAdd(loss, lp);
    }
}

// ---------------- scan: shuffle-based (R10 version) ----------------
__global__ __launch_bounds__(1024) void scan_kernel(const int* __restrict__ bins,
                                                    const float* __restrict__ cluster_size,
                                                    const float* __restrict__ loss,
                                                    int* __restrict__ offsets,
                                                    int* __restrict__ cursor,
                                                    float* __restrict__ out_cs,
                                                    float* __restrict__ ntot,
                                                    float* __restrict__ out_loss) {
    __shared__ int   wtot[16];
    __shared__ float fred[16];
    int t = threadIdx.x;
    int lane = t & 63, wv = t >> 6;
    int b[4];
    float cs[4];
    float csum = 0.f;
    int s = 0;
    #pragma unroll
    for (int e = 0; e < 4; ++e) {
        b[e] = bins[t * 4 + e];
        s += b[e];
        cs[e] = cluster_size[t * 4 + e] * DECAYF + (1.0f - DECAYF) * (float)b[e];
        csum += cs[e];
    }
    int sc = s;
    #pragma unroll
    for (int off = 1; off < 64; off <<= 1) {
        int v = __shfl_up(sc, off, 64);
        if (lane >= off) sc += v;
    }
    float fc = csum;
    #pragma unroll
    for (int off = 32; off > 0; off >>= 1) fc += __shfl_down(fc, off, 64);
    if (lane == 63) wtot[wv] = sc;
    if (lane == 0) fred[wv] = fc;
    __syncthreads();
    if (t < 16) {
        int v = wtot[t];
        int scv = v;
        #pragma unroll
        for (int off = 1; off < 16; off <<= 1) {
            int u = __shfl_up(scv, off, 64);
            if (t >= off) scv += u;
        }
        wtot[t] = scv - v;
    }
    if (t == 0) {
        float tot = 0.f;
        #pragma unroll
        for (int i = 0; i < 16; ++i) tot += fred[i];
        *ntot = tot;
        *out_loss = COMMITW * (*loss) / (float)((size_t)NROWS * DIM);
    }
    __syncthreads();
    int ex = sc - s + wtot[wv];
    #pragma unroll
    for (int e = 0; e < 4; ++e) {
        offsets[t * 4 + e] = ex;
        cursor[t * 4 + e] = ex;
        out_cs[t * 4 + e] = cs[e];
        ex += b[e];
    }
}

// ---------------- reorder rows by code ----------------
__global__ __launch_bounds__(256) void reorder_kernel(const int* __restrict__ ind,
                                                      int* __restrict__ cursor,
                                                      int* __restrict__ rowids,
                                                      int* __restrict__ codesorted) {
    int row = blockIdx.x * 256 + threadIdx.x;
    int k = ind[row];
    int pos = atomicAdd(&cursor[k], 1);
    rowids[pos] = row;
    codesorted[pos] = k;
}

// ---------------- segmented esum + out_q: fixed 16-row windows (R10) -------
#define WROWS 16
__global__ __launch_bounds__(256) void segred_kernel(const float* __restrict__ x,
                                                     const float* __restrict__ embed,
                                                     const int* __restrict__ rowids,
                                                     const int* __restrict__ codesorted,
                                                     const int* __restrict__ offsets,
                                                     const int* __restrict__ bins,
                                                     float* __restrict__ esum,
                                                     float* __restrict__ out_q) {
    int tid = threadIdx.x;
    int lane = tid & 63;
    int wv = blockIdx.x * 4 + (tid >> 6);
    int w0 = wv * WROWS;

    int i16 = lane & (WROWS - 1);
    int rowv = rowids[w0 + i16];
    int kv   = codesorted[w0 + i16];

    float2 xv[WROWS];
    #pragma unroll
    for (int i = 0; i < WROWS; ++i) {
        int row = __shfl(rowv, i, 64);
        xv[i] = ((const float2*)(x + (size_t)row * DIM))[lane];
    }

    int curk = __shfl(kv, 0, 64);
    float2 qv = ((const float2*)(embed + (size_t)curk * DIM))[lane];
    float2 acc = {0.f, 0.f};

    #pragma unroll
    for (int i = 0; i < WROWS; ++i) {
        int row = __shfl(rowv, i, 64);
        int k   = __shfl(kv, i, 64);
        if (k != curk) {
            int sbeg = offsets[curk];
            int send = sbeg + bins[curk];
            float* ep = esum + (size_t)curk * DIM + lane * 2;
            if (sbeg >= w0 && send <= w0 + WROWS) {
                *(float2*)ep = acc;
            } else {
                atomicAdd(ep, acc.x);
                atomicAdd(ep + 1, acc.y);
            }
            curk = k;
            acc = (float2){0.f, 0.f};
            qv = ((const float2*)(embed + (size_t)curk * DIM))[lane];
        }
        acc.x += xv[i].x;
        acc.y += xv[i].y;
        ((float2*)(out_q + (size_t)row * DIM))[lane] = qv;
    }
    {
        int sbeg = offsets[curk];
        int send = sbeg + bins[curk];
        float* ep = esum + (size_t)curk * DIM + lane * 2;
        if (sbeg >= w0 && send <= w0 + WROWS) {
            *(float2*)ep = acc;
        } else {
            atomicAdd(ep, acc.x);
            atomicAdd(ep + 1, acc.y);
        }
    }
}

// ---------------- norm: out_norm from esum (streaming, R10) ----------------
__global__ __launch_bounds__(256) void norm_kernel(const float* __restrict__ esum,
                                                   const float* __restrict__ embed_avg,
                                                   const float* __restrict__ out_cs,
                                                   const float* __restrict__ ntot,
                                                   float* __restrict__ out_norm) {
    int idx = blockIdx.x * 256 + threadIdx.x;
    int k = idx >> 6;
    float nt = *ntot;
    float cs = out_cs[k];
    float cluster = (cs + EPSF) / (nt + (float)KCODES * EPSF) * nt;
    float inv = 1.0f / cluster;
    float2 es = ((const float2*)esum)[idx];
    float2 ea = ((const float2*)embed_avg)[idx];
    float2 o;
    o.x = (ea.x * DECAYF + (1.0f - DECAYF) * es.x) * inv;
    o.y = (ea.y * DECAYF + (1.0f - DECAYF) * es.y) * inv;
    ((float2*)out_norm)[idx] = o;
}

extern "C" void kernel_launch(void* const* d_in, const int* in_sizes, int n_in,
                              void* d_out, int out_size, void* d_ws, size_t ws_size,
                              hipStream_t stream) {
    const float* x            = (const float*)d_in[0];
    const float* embed        = (const float*)d_in[1];
    const float* cluster_size = (const float*)d_in[2];
    const float* embed_avg    = (const float*)d_in[3];

    float* out      = (float*)d_out;
    float* out_q    = out;                               // 4194304
    float* out_ind  = out + 4194304;                     // 32768
    float* out_loss = out_ind + 32768;                   // 1
    float* out_cs   = out_loss + 1;                      // 4096
    float* out_norm = out_cs + 4096;                     // 524288

    // workspace layout (bytes)
    char* ws = (char*)d_ws;
    _Float16* estg = (_Float16*)ws;                      // 2,097,152
    float* e2h   = (float*)(ws + 2097152);               // 16,384
    int*   ind   = (int*)(ws + 2113536);                 // 131,072
    int*   offsets = (int*)(ws + 2244608);               // 16,384
    int*   cursor  = (int*)(ws + 2260992);               // 16,384
    int*   rowids  = (int*)(ws + 2277376);               // 131,072
    int*   codesorted = (int*)(ws + 2408448);            // 131,072
    float* loss  = (float*)(ws + 2539520);               // 4 (pad to 256)
    float* ntot  = loss + 1;
    int*   bins  = (int*)(ws + 2539776);                 // 16,384
    float* esum  = (float*)(ws + 2556160);               // 2,097,152

    // zero loss/pad + bins + esum (contiguous)
    hipMemsetAsync(ws + 2539520, 0, 256 + 16384 + 2097152, stream);

    esplit_kernel<<<KCODES / 4, 256, 0, stream>>>(embed, estg, e2h);
    argmax_kernel<<<NROWS / 128, 512, 0, stream>>>(x, estg, e2h, ind, out_ind,
                                                   bins, loss);
    scan_kernel<<<1, 1024, 0, stream>>>(bins, cluster_size, loss, offsets, cursor,
                                        out_cs, ntot, out_loss);
    reorder_kernel<<<NROWS / 256, 256, 0, stream>>>(ind, cursor, rowids, codesorted);
    segred_kernel<<<NROWS / WROWS / 4, 256, 0, stream>>>(x, embed, rowids, codesorted,
                                                         offsets, bins, esum, out_q);
    norm_kernel<<<KCODES * DIM / 2 / 256, 256, 0, stream>>>(esum, embed_avg, out_cs,
                                                            ntot, out_norm);
}

// Round 14
// 205.928 us; speedup vs baseline: 1.8975x; 1.5946x over previous
//
#include <hip/hip_runtime.h>

#define NROWS 32768
#define DIM   128
#define KCODES 4096
#define DECAYF 0.8f
#define EPSF 1e-5f
#define COMMITW 0.25f

typedef _Float16 half8 __attribute__((ext_vector_type(8)));
typedef _Float16 half2v __attribute__((ext_vector_type(2)));
typedef float float4v __attribute__((ext_vector_type(4)));

// ---------------- embed -> staged split planes + e2 (R10 layout) -----------
// estg (halves): [chunk][slice][code6][8], slice = pl*16 + ks*4 + q.
// Exactly the 16x16x32 MFMA B-fragment order -> coalesced register loads.
__global__ __launch_bounds__(256) void esplit_kernel(const float* __restrict__ embed,
                                                     _Float16* __restrict__ estg,
                                                     float* __restrict__ e2h) {
    int code = blockIdx.x * 4 + (threadIdx.x >> 6);
    int lane = threadIdx.x & 63;
    float2 v = ((const float2*)(embed + (size_t)code * DIM))[lane];
    float s = v.x * v.x + v.y * v.y;
    #pragma unroll
    for (int off = 32; off > 0; off >>= 1) s += __shfl_down(s, off, 64);
    if (lane == 0) e2h[code] = 0.5f * s;

    int d = lane * 2;
    int ks = d >> 5, q = (d >> 3) & 3, j = d & 7;
    _Float16 h0 = (_Float16)v.x, l0 = (_Float16)(v.x - (float)h0);
    _Float16 h1 = (_Float16)v.y, l1 = (_Float16)(v.y - (float)h1);
    int chunk = code >> 6, c6 = code & 63;
    size_t base = (size_t)chunk * 16384;
    size_t hidx = base + (size_t)(( 0 + ks * 4 + q) * 64 + c6) * 8 + j;
    size_t lidx = base + (size_t)((16 + ks * 4 + q) * 64 + c6) * 8 + j;
    *(half2v*)&estg[hidx] = (half2v){h0, h1};
    *(half2v*)&estg[lidx] = (half2v){l0, l1};
}

// ---------------- MFMA argmax: 16x16x32, 128 rows/block (R10 + issue fix) --
// score = x.e - 0.5|e|^2 (folded into acc init). fp16 2-way split, 3 products.
// 512 thr / 8 waves: wave w -> code-tile j=w&3, row-half rh=w>>2. 64 rows
// A-resident/wave (128 VGPR). Register dbuf for B, no per-chunk barriers.
// ISSUE FIX vs R10: product-major inner loop (hh x4rt, lh x4rt, hl x4rt) so
// 4 independent MFMAs separate dependent writes to the same acc chain
// (R10's rt-major order put dependent triples back-to-back).
__global__ __launch_bounds__(512, 2) void argmax_kernel(const float* __restrict__ x,
                                                        const _Float16* __restrict__ estg,
                                                        const float* __restrict__ e2h,
                                                        int* __restrict__ ind,
                                                        float* __restrict__ out_ind,
                                                        int* __restrict__ bins,
                                                        float* __restrict__ loss) {
    __shared__ float rv[8][64];
    __shared__ int   ri[8][64];
    __shared__ float x2s[128];

    int tid = threadIdx.x;
    int lane = tid & 63;
    int w = tid >> 6;
    int j = w & 3;
    int rh = w >> 2;
    int m15 = lane & 15;
    int q = (lane >> 4) & 3;
    int n0 = blockIdx.x * 128;

    // A frags for this wave's 64 rows (rows n0 + rh*64 + rt*16 + m15)
    half8 Ah[4][4], Al[4][4];
    float xsq[4];
    #pragma unroll
    for (int rt = 0; rt < 4; ++rt) {
        xsq[rt] = 0.f;
        #pragma unroll
        for (int ks = 0; ks < 4; ++ks) {
            const float* p = x + (size_t)(n0 + rh * 64 + rt * 16 + m15) * DIM + ks * 32 + q * 8;
            float4 a = *(const float4*)p;
            float4 b = *(const float4*)(p + 4);
            float f[8] = {a.x, a.y, a.z, a.w, b.x, b.y, b.z, b.w};
            half8 H, L;
            #pragma unroll
            for (int e = 0; e < 8; ++e) {
                _Float16 h = (_Float16)f[e];
                H[e] = h;
                L[e] = (_Float16)(f[e] - (float)h);
                xsq[rt] += f[e] * f[e];
            }
            Ah[rt][ks] = H;
            Al[rt][ks] = L;
        }
        xsq[rt] += __shfl_xor(xsq[rt], 16, 64);
        xsq[rt] += __shfl_xor(xsq[rt], 32, 64);
    }
    if (j == 0 && lane < 16) {
        #pragma unroll
        for (int rt = 0; rt < 4; ++rt) x2s[rh * 64 + rt * 16 + m15] = xsq[rt];
    }

    float best[4][4];
    int   bidx[4][4];
    #pragma unroll
    for (int rt = 0; rt < 4; ++rt)
        #pragma unroll
        for (int r = 0; r < 4; ++r) { best[rt][r] = -3.0e38f; bidx[rt][r] = 0; }

    // B fragment base for this wave/lane within a chunk
    const _Float16* bbase = estg + (size_t)(j * 16 + m15) * 8 + (size_t)q * 512;
    const int cm = j * 16 + m15;

    half8 B0h[4], B0l[4], B1h[4], B1l[4];
    float e20, e21;

    // prefetch chunk 0 -> buf0
    {
        const _Float16* cb = bbase;
        #pragma unroll
        for (int ks = 0; ks < 4; ++ks) {
            B0h[ks] = *(const half8*)(cb + ks * 2048);
            B0l[ks] = *(const half8*)(cb + 8192 + ks * 2048);
        }
        e20 = e2h[cm];
    }

    #pragma unroll 1
    for (int ch = 0; ch < 64; ch += 2) {
        // prefetch ch+1 -> buf1
        {
            const _Float16* cb = bbase + (size_t)(ch + 1) * 16384;
            #pragma unroll
            for (int ks = 0; ks < 4; ++ks) {
                B1h[ks] = *(const half8*)(cb + ks * 2048);
                B1l[ks] = *(const half8*)(cb + 8192 + ks * 2048);
            }
            e21 = e2h[(ch + 1) * 64 + cm];
        }
        // compute ch from buf0 — product-major: 4 independent acc chains
        {
            float4v acc[4];
            #pragma unroll
            for (int rt = 0; rt < 4; ++rt) acc[rt] = (float4v){-e20, -e20, -e20, -e20};
            #pragma unroll
            for (int ks = 0; ks < 4; ++ks) {
                #pragma unroll
                for (int rt = 0; rt < 4; ++rt)
                    acc[rt] = __builtin_amdgcn_mfma_f32_16x16x32_f16(Ah[rt][ks], B0h[ks], acc[rt], 0, 0, 0);
                #pragma unroll
                for (int rt = 0; rt < 4; ++rt)
                    acc[rt] = __builtin_amdgcn_mfma_f32_16x16x32_f16(Al[rt][ks], B0h[ks], acc[rt], 0, 0, 0);
                #pragma unroll
                for (int rt = 0; rt < 4; ++rt)
                    acc[rt] = __builtin_amdgcn_mfma_f32_16x16x32_f16(Ah[rt][ks], B0l[ks], acc[rt], 0, 0, 0);
            }
            int c = ch * 64 + cm;
            #pragma unroll
            for (int rt = 0; rt < 4; ++rt)
                #pragma unroll
                for (int r = 0; r < 4; ++r) {
                    float s = acc[rt][r];
                    if (s > best[rt][r]) { best[rt][r] = s; bidx[rt][r] = c; }
                }
        }
        // prefetch ch+2 -> buf0
        if (ch + 2 < 64) {
            const _Float16* cb = bbase + (size_t)(ch + 2) * 16384;
            #pragma unroll
            for (int ks = 0; ks < 4; ++ks) {
                B0h[ks] = *(const half8*)(cb + ks * 2048);
                B0l[ks] = *(const half8*)(cb + 8192 + ks * 2048);
            }
            e20 = e2h[(ch + 2) * 64 + cm];
        }
        // compute ch+1 from buf1
        {
            float4v acc[4];
            #pragma unroll
            for (int rt = 0; rt < 4; ++rt) acc[rt] = (float4v){-e21, -e21, -e21, -e21};
            #pragma unroll
            for (int ks = 0; ks < 4; ++ks) {
                #pragma unroll
                for (int rt = 0; rt < 4; ++rt)
                    acc[rt] = __builtin_amdgcn_mfma_f32_16x16x32_f16(Ah[rt][ks], B1h[ks], acc[rt], 0, 0, 0);
                #pragma unroll
                for (int rt = 0; rt < 4; ++rt)
                    acc[rt] = __builtin_amdgcn_mfma_f32_16x16x32_f16(Al[rt][ks], B1h[ks], acc[rt], 0, 0, 0);
                #pragma unroll
                for (int rt = 0; rt < 4; ++rt)
                    acc[rt] = __builtin_amdgcn_mfma_f32_16x16x32_f16(Ah[rt][ks], B1l[ks], acc[rt], 0, 0, 0);
            }
            int c = (ch + 1) * 64 + cm;
            #pragma unroll
            for (int rt = 0; rt < 4; ++rt)
                #pragma unroll
                for (int r = 0; r < 4; ++r) {
                    float s = acc[rt][r];
                    if (s > best[rt][r]) { best[rt][r] = s; bidx[rt][r] = c; }
                }
        }
    }

    // reduce across the 16 code-lanes (m15); min index on ties
    #pragma unroll
    for (int rt = 0; rt < 4; ++rt)
        #pragma unroll
        for (int r = 0; r < 4; ++r) {
            float bv = best[rt][r];
            int   bi = bidx[rt][r];
            #pragma unroll
            for (int m = 1; m <= 8; m <<= 1) {
                float ov = __shfl_xor(bv, m, 64);
                int   oi = __shfl_xor(bi, m, 64);
                if (ov > bv || (ov == bv && oi < bi)) { bv = ov; bi = oi; }
            }
            if (m15 == 0) {
                int rl = rt * 16 + q * 4 + r;
                rv[w][rl] = bv;
                ri[w][rl] = bi;
            }
        }
    __syncthreads();
    if (tid < 128) {
        int rhh = tid >> 6;
        int rl  = tid & 63;
        float bv = rv[rhh * 4][rl];
        int   bi = ri[rhh * 4][rl];
        #pragma unroll
        for (int jj = 1; jj < 4; ++jj) {
            float ov = rv[rhh * 4 + jj][rl];
            int   oi = ri[rhh * 4 + jj][rl];
            if (ov > bv || (ov == bv && oi < bi)) { bv = ov; bi = oi; }
        }
        ind[n0 + tid] = bi;
        out_ind[n0 + tid] = (float)bi;
        atomicAdd(&bins[bi], 1);
        float lp = x2s[tid] - 2.0f * bv;
        #pragma unroll
        for (int off = 32; off > 0; off >>= 1) lp += __shfl_down(lp, off, 64);
        if ((tid & 63) == 0) atomicAdd(loss, lp);
    }
}

// ---------------- scan: shuffle-based ----------------
__global__ __launch_bounds__(1024) void scan_kernel(const int* __restrict__ bins,
                                                    const float* __restrict__ cluster_size,
                                                    const float* __restrict__ loss,
                                                    int* __restrict__ offsets,
                                                    int* __restrict__ cursor,
                                                    float* __restrict__ out_cs,
                                                    float* __restrict__ ntot,
                                                    float* __restrict__ out_loss) {
    __shared__ int   wtot[16];
    __shared__ float fred[16];
    int t = threadIdx.x;
    int lane = t & 63, wv = t >> 6;
    int b[4];
    float cs[4];
    float csum = 0.f;
    int s = 0;
    #pragma unroll
    for (int e = 0; e < 4; ++e) {
        b[e] = bins[t * 4 + e];
        s += b[e];
        cs[e] = cluster_size[t * 4 + e] * DECAYF + (1.0f - DECAYF) * (float)b[e];
        csum += cs[e];
    }
    int sc = s;
    #pragma unroll
    for (int off = 1; off < 64; off <<= 1) {
        int v = __shfl_up(sc, off, 64);
        if (lane >= off) sc += v;
    }
    float fc = csum;
    #pragma unroll
    for (int off = 32; off > 0; off >>= 1) fc += __shfl_down(fc, off, 64);
    if (lane == 63) wtot[wv] = sc;
    if (lane == 0) fred[wv] = fc;
    __syncthreads();
    if (t < 16) {
        int v = wtot[t];
        int scv = v;
        #pragma unroll
        for (int off = 1; off < 16; off <<= 1) {
            int u = __shfl_up(scv, off, 64);
            if (t >= off) scv += u;
        }
        wtot[t] = scv - v;
    }
    if (t == 0) {
        float tot = 0.f;
        #pragma unroll
        for (int i = 0; i < 16; ++i) tot += fred[i];
        *ntot = tot;
        *out_loss = COMMITW * (*loss) / (float)((size_t)NROWS * DIM);
    }
    __syncthreads();
    int ex = sc - s + wtot[wv];
    #pragma unroll
    for (int e = 0; e < 4; ++e) {
        offsets[t * 4 + e] = ex;
        cursor[t * 4 + e] = ex;
        out_cs[t * 4 + e] = cs[e];
        ex += b[e];
    }
}

// ---------------- reorder rows by code ----------------
__global__ __launch_bounds__(256) void reorder_kernel(const int* __restrict__ ind,
                                                      int* __restrict__ cursor,
                                                      int* __restrict__ rowids,
                                                      int* __restrict__ codesorted) {
    int row = blockIdx.x * 256 + threadIdx.x;
    int k = ind[row];
    int pos = atomicAdd(&cursor[k], 1);
    rowids[pos] = row;
    codesorted[pos] = k;
}

// ---------------- segmented esum + out_q: fixed 16-row windows -------------
#define WROWS 16
__global__ __launch_bounds__(256) void segred_kernel(const float* __restrict__ x,
                                                     const float* __restrict__ embed,
                                                     const int* __restrict__ rowids,
                                                     const int* __restrict__ codesorted,
                                                     const int* __restrict__ offsets,
                                                     const int* __restrict__ bins,
                                                     float* __restrict__ esum,
                                                     float* __restrict__ out_q) {
    int tid = threadIdx.x;
    int lane = tid & 63;
    int wv = blockIdx.x * 4 + (tid >> 6);
    int w0 = wv * WROWS;

    int i16 = lane & (WROWS - 1);
    int rowv = rowids[w0 + i16];
    int kv   = codesorted[w0 + i16];

    float2 xv[WROWS];
    #pragma unroll
    for (int i = 0; i < WROWS; ++i) {
        int row = __shfl(rowv, i, 64);
        xv[i] = ((const float2*)(x + (size_t)row * DIM))[lane];
    }

    int curk = __shfl(kv, 0, 64);
    float2 qv = ((const float2*)(embed + (size_t)curk * DIM))[lane];
    float2 acc = {0.f, 0.f};

    #pragma unroll
    for (int i = 0; i < WROWS; ++i) {
        int row = __shfl(rowv, i, 64);
        int k   = __shfl(kv, i, 64);
        if (k != curk) {
            int sbeg = offsets[curk];
            int send = sbeg + bins[curk];
            float* ep = esum + (size_t)curk * DIM + lane * 2;
            if (sbeg >= w0 && send <= w0 + WROWS) {
                *(float2*)ep = acc;
            } else {
                atomicAdd(ep, acc.x);
                atomicAdd(ep + 1, acc.y);
            }
            curk = k;
            acc = (float2){0.f, 0.f};
            qv = ((const float2*)(embed + (size_t)curk * DIM))[lane];
        }
        acc.x += xv[i].x;
        acc.y += xv[i].y;
        ((float2*)(out_q + (size_t)row * DIM))[lane] = qv;
    }
    {
        int sbeg = offsets[curk];
        int send = sbeg + bins[curk];
        float* ep = esum + (size_t)curk * DIM + lane * 2;
        if (sbeg >= w0 && send <= w0 + WROWS) {
            *(float2*)ep = acc;
        } else {
            atomicAdd(ep, acc.x);
            atomicAdd(ep + 1, acc.y);
        }
    }
}

// ---------------- norm: out_norm from esum (float4 streaming) --------------
__global__ __launch_bounds__(256) void norm_kernel(const float* __restrict__ esum,
                                                   const float* __restrict__ embed_avg,
                                                   const float* __restrict__ out_cs,
                                                   const float* __restrict__ ntot,
                                                   float* __restrict__ out_norm) {
    int idx = blockIdx.x * 256 + threadIdx.x;   // float4 index
    int k = idx >> 5;
    float nt = *ntot;
    float cs = out_cs[k];
    float cluster = (cs + EPSF) / (nt + (float)KCODES * EPSF) * nt;
    float inv = 1.0f / cluster;
    float4 es = ((const float4*)esum)[idx];
    float4 ea = ((const float4*)embed_avg)[idx];
    float4 o;
    o.x = (ea.x * DECAYF + (1.0f - DECAYF) * es.x) * inv;
    o.y = (ea.y * DECAYF + (1.0f - DECAYF) * es.y) * inv;
    o.z = (ea.z * DECAYF + (1.0f - DECAYF) * es.z) * inv;
    o.w = (ea.w * DECAYF + (1.0f - DECAYF) * es.w) * inv;
    ((float4*)out_norm)[idx] = o;
}

extern "C" void kernel_launch(void* const* d_in, const int* in_sizes, int n_in,
                              void* d_out, int out_size, void* d_ws, size_t ws_size,
                              hipStream_t stream) {
    const float* x            = (const float*)d_in[0];
    const float* embed        = (const float*)d_in[1];
    const float* cluster_size = (const float*)d_in[2];
    const float* embed_avg    = (const float*)d_in[3];

    float* out      = (float*)d_out;
    float* out_q    = out;                               // 4194304
    float* out_ind  = out + 4194304;                     // 32768
    float* out_loss = out_ind + 32768;                   // 1
    float* out_cs   = out_loss + 1;                      // 4096
    float* out_norm = out_cs + 4096;                     // 524288

    // workspace layout (bytes)
    char* ws = (char*)d_ws;
    _Float16* estg = (_Float16*)ws;                      // 2,097,152
    float* e2h   = (float*)(ws + 2097152);               // 16,384
    int*   ind   = (int*)(ws + 2113536);                 // 131,072
    int*   offsets = (int*)(ws + 2244608);               // 16,384
    int*   cursor  = (int*)(ws + 2260992);               // 16,384
    int*   rowids  = (int*)(ws + 2277376);               // 131,072
    int*   codesorted = (int*)(ws + 2408448);            // 131,072
    float* loss  = (float*)(ws + 2539520);               // 4 (pad to 256)
    float* ntot  = loss + 1;
    int*   bins  = (int*)(ws + 2539776);                 // 16,384
    float* esum  = (float*)(ws + 2556160);               // 2,097,152

    // zero loss/pad + bins + esum (contiguous)
    hipMemsetAsync(ws + 2539520, 0, 256 + 16384 + 2097152, stream);

    esplit_kernel<<<KCODES / 4, 256, 0, stream>>>(embed, estg, e2h);
    argmax_kernel<<<NROWS / 128, 512, 0, stream>>>(x, estg, e2h, ind, out_ind,
                                                   bins, loss);
    scan_kernel<<<1, 1024, 0, stream>>>(bins, cluster_size, loss, offsets, cursor,
                                        out_cs, ntot, out_loss);
    reorder_kernel<<<NROWS / 256, 256, 0, stream>>>(ind, cursor, rowids, codesorted);
    segred_kernel<<<NROWS / WROWS / 4, 256, 0, stream>>>(x, embed, rowids, codesorted,
                                                         offsets, bins, esum, out_q);
    norm_kernel<<<KCODES * DIM / 4 / 256, 256, 0, stream>>>(esum, embed_avg, out_cs,
                                                            ntot, out_norm);
}

// Round 15
// 196.154 us; speedup vs baseline: 1.9921x; 1.0498x over previous
//
#include <hip/hip_runtime.h>

#define NROWS 32768
#define DIM   128
#define KCODES 4096
#define DECAYF 0.8f
#define EPSF 1e-5f
#define COMMITW 0.25f

typedef _Float16 half8 __attribute__((ext_vector_type(8)));
typedef _Float16 half2v __attribute__((ext_vector_type(2)));
typedef float float4v __attribute__((ext_vector_type(4)));

// ---------------- embed -> staged split planes + e2 + ws zeroing -----------
// estg (halves): [chunk][slice][code6][8], slice = pl*16 + ks*4 + q.
// Exactly the 16x16x32 MFMA B-fragment order -> coalesced register loads.
// Also zeroes esum (1 float2/thread) and bins/loss (first 4160 ints),
// replacing the separate hipMemsetAsync dispatch.
__global__ __launch_bounds__(256) void esplit_kernel(const float* __restrict__ embed,
                                                     _Float16* __restrict__ estg,
                                                     float* __restrict__ e2h,
                                                     float2* __restrict__ esum2,
                                                     int* __restrict__ zmisc) {
    int gid = blockIdx.x * 256 + threadIdx.x;
    esum2[gid] = (float2){0.f, 0.f};
    if (gid < 4160) zmisc[gid] = 0;

    int code = blockIdx.x * 4 + (threadIdx.x >> 6);
    int lane = threadIdx.x & 63;
    float2 v = ((const float2*)(embed + (size_t)code * DIM))[lane];
    float s = v.x * v.x + v.y * v.y;
    #pragma unroll
    for (int off = 32; off > 0; off >>= 1) s += __shfl_down(s, off, 64);
    if (lane == 0) e2h[code] = 0.5f * s;

    int d = lane * 2;
    int ks = d >> 5, q = (d >> 3) & 3, j = d & 7;
    _Float16 h0 = (_Float16)v.x, l0 = (_Float16)(v.x - (float)h0);
    _Float16 h1 = (_Float16)v.y, l1 = (_Float16)(v.y - (float)h1);
    int chunk = code >> 6, c6 = code & 63;
    size_t base = (size_t)chunk * 16384;
    size_t hidx = base + (size_t)(( 0 + ks * 4 + q) * 64 + c6) * 8 + j;
    size_t lidx = base + (size_t)((16 + ks * 4 + q) * 64 + c6) * 8 + j;
    *(half2v*)&estg[hidx] = (half2v){h0, h1};
    *(half2v*)&estg[lidx] = (half2v){l0, l1};
}

// ---------------- MFMA argmax: 16x16x32, 128 rows/block (R10 verbatim) -----
// score = x.e - 0.5|e|^2 (folded into acc init). fp16 2-way split, 3 products
// in rt-major order — R14's product-major reorder induced scratch spills
// (WRITE_SIZE 1.2->7.4MB); do NOT reorder this loop.
// 512 thr / 8 waves: wave w -> code-tile j=w&3, row-half rh=w>>2. 64 rows
// A-resident/wave (128 VGPR). Register dbuf for B, no per-chunk barriers.
__global__ __launch_bounds__(512, 2) void argmax_kernel(const float* __restrict__ x,
                                                        const _Float16* __restrict__ estg,
                                                        const float* __restrict__ e2h,
                                                        int* __restrict__ ind,
                                                        float* __restrict__ out_ind,
                                                        int* __restrict__ bins,
                                                        float* __restrict__ loss) {
    __shared__ float rv[8][64];
    __shared__ int   ri[8][64];
    __shared__ float x2s[128];

    int tid = threadIdx.x;
    int lane = tid & 63;
    int w = tid >> 6;
    int j = w & 3;
    int rh = w >> 2;
    int m15 = lane & 15;
    int q = (lane >> 4) & 3;
    int n0 = blockIdx.x * 128;

    half8 Ah[4][4], Al[4][4];
    float xsq[4];
    #pragma unroll
    for (int rt = 0; rt < 4; ++rt) {
        xsq[rt] = 0.f;
        #pragma unroll
        for (int ks = 0; ks < 4; ++ks) {
            const float* p = x + (size_t)(n0 + rh * 64 + rt * 16 + m15) * DIM + ks * 32 + q * 8;
            float4 a = *(const float4*)p;
            float4 b = *(const float4*)(p + 4);
            float f[8] = {a.x, a.y, a.z, a.w, b.x, b.y, b.z, b.w};
            half8 H, L;
            #pragma unroll
            for (int e = 0; e < 8; ++e) {
                _Float16 h = (_Float16)f[e];
                H[e] = h;
                L[e] = (_Float16)(f[e] - (float)h);
                xsq[rt] += f[e] * f[e];
            }
            Ah[rt][ks] = H;
            Al[rt][ks] = L;
        }
        xsq[rt] += __shfl_xor(xsq[rt], 16, 64);
        xsq[rt] += __shfl_xor(xsq[rt], 32, 64);
    }
    if (j == 0 && lane < 16) {
        #pragma unroll
        for (int rt = 0; rt < 4; ++rt) x2s[rh * 64 + rt * 16 + m15] = xsq[rt];
    }

    float best[4][4];
    int   bidx[4][4];
    #pragma unroll
    for (int rt = 0; rt < 4; ++rt)
        #pragma unroll
        for (int r = 0; r < 4; ++r) { best[rt][r] = -3.0e38f; bidx[rt][r] = 0; }

    const _Float16* bbase = estg + (size_t)(j * 16 + m15) * 8 + (size_t)q * 512;
    const int cm = j * 16 + m15;

    half8 B0h[4], B0l[4], B1h[4], B1l[4];
    float e20, e21;

    {
        const _Float16* cb = bbase;
        #pragma unroll
        for (int ks = 0; ks < 4; ++ks) {
            B0h[ks] = *(const half8*)(cb + ks * 2048);
            B0l[ks] = *(const half8*)(cb + 8192 + ks * 2048);
        }
        e20 = e2h[cm];
    }

    #pragma unroll 1
    for (int ch = 0; ch < 64; ch += 2) {
        {
            const _Float16* cb = bbase + (size_t)(ch + 1) * 16384;
            #pragma unroll
            for (int ks = 0; ks < 4; ++ks) {
                B1h[ks] = *(const half8*)(cb + ks * 2048);
                B1l[ks] = *(const half8*)(cb + 8192 + ks * 2048);
            }
            e21 = e2h[(ch + 1) * 64 + cm];
        }
        {
            float4v acc[4];
            #pragma unroll
            for (int rt = 0; rt < 4; ++rt) acc[rt] = (float4v){-e20, -e20, -e20, -e20};
            #pragma unroll
            for (int ks = 0; ks < 4; ++ks)
                #pragma unroll
                for (int rt = 0; rt < 4; ++rt) {
                    acc[rt] = __builtin_amdgcn_mfma_f32_16x16x32_f16(Ah[rt][ks], B0h[ks], acc[rt], 0, 0, 0);
                    acc[rt] = __builtin_amdgcn_mfma_f32_16x16x32_f16(Al[rt][ks], B0h[ks], acc[rt], 0, 0, 0);
                    acc[rt] = __builtin_amdgcn_mfma_f32_16x16x32_f16(Ah[rt][ks], B0l[ks], acc[rt], 0, 0, 0);
                }
            int c = ch * 64 + cm;
            #pragma unroll
            for (int rt = 0; rt < 4; ++rt)
                #pragma unroll
                for (int r = 0; r < 4; ++r) {
                    float s = acc[rt][r];
                    if (s > best[rt][r]) { best[rt][r] = s; bidx[rt][r] = c; }
                }
        }
        if (ch + 2 < 64) {
            const _Float16* cb = bbase + (size_t)(ch + 2) * 16384;
            #pragma unroll
            for (int ks = 0; ks < 4; ++ks) {
                B0h[ks] = *(const half8*)(cb + ks * 2048);
                B0l[ks] = *(const half8*)(cb + 8192 + ks * 2048);
            }
            e20 = e2h[(ch + 2) * 64 + cm];
        }
        {
            float4v acc[4];
            #pragma unroll
            for (int rt = 0; rt < 4; ++rt) acc[rt] = (float4v){-e21, -e21, -e21, -e21};
            #pragma unroll
            for (int ks = 0; ks < 4; ++ks)
                #pragma unroll
                for (int rt = 0; rt < 4; ++rt) {
                    acc[rt] = __builtin_amdgcn_mfma_f32_16x16x32_f16(Ah[rt][ks], B1h[ks], acc[rt], 0, 0, 0);
                    acc[rt] = __builtin_amdgcn_mfma_f32_16x16x32_f16(Al[rt][ks], B1h[ks], acc[rt], 0, 0, 0);
                    acc[rt] = __builtin_amdgcn_mfma_f32_16x16x32_f16(Ah[rt][ks], B1l[ks], acc[rt], 0, 0, 0);
                }
            int c = (ch + 1) * 64 + cm;
            #pragma unroll
            for (int rt = 0; rt < 4; ++rt)
                #pragma unroll
                for (int r = 0; r < 4; ++r) {
                    float s = acc[rt][r];
                    if (s > best[rt][r]) { best[rt][r] = s; bidx[rt][r] = c; }
                }
        }
    }

    #pragma unroll
    for (int rt = 0; rt < 4; ++rt)
        #pragma unroll
        for (int r = 0; r < 4; ++r) {
            float bv = best[rt][r];
            int   bi = bidx[rt][r];
            #pragma unroll
            for (int m = 1; m <= 8; m <<= 1) {
                float ov = __shfl_xor(bv, m, 64);
                int   oi = __shfl_xor(bi, m, 64);
                if (ov > bv || (ov == bv && oi < bi)) { bv = ov; bi = oi; }
            }
            if (m15 == 0) {
                int rl = rt * 16 + q * 4 + r;
                rv[w][rl] = bv;
                ri[w][rl] = bi;
            }
        }
    __syncthreads();
    if (tid < 128) {
        int rhh = tid >> 6;
        int rl  = tid & 63;
        float bv = rv[rhh * 4][rl];
        int   bi = ri[rhh * 4][rl];
        #pragma unroll
        for (int jj = 1; jj < 4; ++jj) {
            float ov = rv[rhh * 4 + jj][rl];
            int   oi = ri[rhh * 4 + jj][rl];
            if (ov > bv || (ov == bv && oi < bi)) { bv = ov; bi = oi; }
        }
        ind[n0 + tid] = bi;
        out_ind[n0 + tid] = (float)bi;
        atomicAdd(&bins[bi], 1);
        float lp = x2s[tid] - 2.0f * bv;
        #pragma unroll
        for (int off = 32; off > 0; off >>= 1) lp += __shfl_down(lp, off, 64);
        if ((tid & 63) == 0) atomicAdd(loss, lp);
    }
}

// ---------------- scan: shuffle-based ----------------
__global__ __launch_bounds__(1024) void scan_kernel(const int* __restrict__ bins,
                                                    const float* __restrict__ cluster_size,
                                                    const float* __restrict__ loss,
                                                    int* __restrict__ offsets,
                                                    int* __restrict__ cursor,
                                                    float* __restrict__ out_cs,
                                                    float* __restrict__ ntot,
                                                    float* __restrict__ out_loss) {
    __shared__ int   wtot[16];
    __shared__ float fred[16];
    int t = threadIdx.x;
    int lane = t & 63, wv = t >> 6;
    int b[4];
    float cs[4];
    float csum = 0.f;
    int s = 0;
    #pragma unroll
    for (int e = 0; e < 4; ++e) {
        b[e] = bins[t * 4 + e];
        s += b[e];
        cs[e] = cluster_size[t * 4 + e] * DECAYF + (1.0f - DECAYF) * (float)b[e];
        csum += cs[e];
    }
    int sc = s;
    #pragma unroll
    for (int off = 1; off < 64; off <<= 1) {
        int v = __shfl_up(sc, off, 64);
        if (lane >= off) sc += v;
    }
    float fc = csum;
    #pragma unroll
    for (int off = 32; off > 0; off >>= 1) fc += __shfl_down(fc, off, 64);
    if (lane == 63) wtot[wv] = sc;
    if (lane == 0) fred[wv] = fc;
    __syncthreads();
    if (t < 16) {
        int v = wtot[t];
        int scv = v;
        #pragma unroll
        for (int off = 1; off < 16; off <<= 1) {
            int u = __shfl_up(scv, off, 64);
            if (t >= off) scv += u;
        }
        wtot[t] = scv - v;
    }
    if (t == 0) {
        float tot = 0.f;
        #pragma unroll
        for (int i = 0; i < 16; ++i) tot += fred[i];
        *ntot = tot;
        *out_loss = COMMITW * (*loss) / (float)((size_t)NROWS * DIM);
    }
    __syncthreads();
    int ex = sc - s + wtot[wv];
    #pragma unroll
    for (int e = 0; e < 4; ++e) {
        offsets[t * 4 + e] = ex;
        cursor[t * 4 + e] = ex;
        out_cs[t * 4 + e] = cs[e];
        ex += b[e];
    }
}

// ---------------- reorder rows by code ----------------
__global__ __launch_bounds__(256) void reorder_kernel(const int* __restrict__ ind,
                                                      int* __restrict__ cursor,
                                                      int* __restrict__ rowids,
                                                      int* __restrict__ codesorted) {
    int row = blockIdx.x * 256 + threadIdx.x;
    int k = ind[row];
    int pos = atomicAdd(&cursor[k], 1);
    rowids[pos] = row;
    codesorted[pos] = k;
}

// ---------------- segmented esum + out_q: fixed 16-row windows -------------
#define WROWS 16
__global__ __launch_bounds__(256) void segred_kernel(const float* __restrict__ x,
                                                     const float* __restrict__ embed,
                                                     const int* __restrict__ rowids,
                                                     const int* __restrict__ codesorted,
                                                     const int* __restrict__ offsets,
                                                     const int* __restrict__ bins,
                                                     float* __restrict__ esum,
                                                     float* __restrict__ out_q) {
    int tid = threadIdx.x;
    int lane = tid & 63;
    int wv = blockIdx.x * 4 + (tid >> 6);
    int w0 = wv * WROWS;

    int i16 = lane & (WROWS - 1);
    int rowv = rowids[w0 + i16];
    int kv   = codesorted[w0 + i16];

    float2 xv[WROWS];
    #pragma unroll
    for (int i = 0; i < WROWS; ++i) {
        int row = __shfl(rowv, i, 64);
        xv[i] = ((const float2*)(x + (size_t)row * DIM))[lane];
    }

    int curk = __shfl(kv, 0, 64);
    float2 qv = ((const float2*)(embed + (size_t)curk * DIM))[lane];
    float2 acc = {0.f, 0.f};

    #pragma unroll
    for (int i = 0; i < WROWS; ++i) {
        int row = __shfl(rowv, i, 64);
        int k   = __shfl(kv, i, 64);
        if (k != curk) {
            int sbeg = offsets[curk];
            int send = sbeg + bins[curk];
            float* ep = esum + (size_t)curk * DIM + lane * 2;
            if (sbeg >= w0 && send <= w0 + WROWS) {
                *(float2*)ep = acc;
            } else {
                atomicAdd(ep, acc.x);
                atomicAdd(ep + 1, acc.y);
            }
            curk = k;
            acc = (float2){0.f, 0.f};
            qv = ((const float2*)(embed + (size_t)curk * DIM))[lane];
        }
        acc.x += xv[i].x;
        acc.y += xv[i].y;
        ((float2*)(out_q + (size_t)row * DIM))[lane] = qv;
    }
    {
        int sbeg = offsets[curk];
        int send = sbeg + bins[curk];
        float* ep = esum + (size_t)curk * DIM + lane * 2;
        if (sbeg >= w0 && send <= w0 + WROWS) {
            *(float2*)ep = acc;
        } else {
            atomicAdd(ep, acc.x);
            atomicAdd(ep + 1, acc.y);
        }
    }
}

// ---------------- norm: out_norm from esum (float4 streaming) --------------
__global__ __launch_bounds__(256) void norm_kernel(const float* __restrict__ esum,
                                                   const float* __restrict__ embed_avg,
                                                   const float* __restrict__ out_cs,
                                                   const float* __restrict__ ntot,
                                                   float* __restrict__ out_norm) {
    int idx = blockIdx.x * 256 + threadIdx.x;   // float4 index
    int k = idx >> 5;
    float nt = *ntot;
    float cs = out_cs[k];
    float cluster = (cs + EPSF) / (nt + (float)KCODES * EPSF) * nt;
    float inv = 1.0f / cluster;
    float4 es = ((const float4*)esum)[idx];
    float4 ea = ((const float4*)embed_avg)[idx];
    float4 o;
    o.x = (ea.x * DECAYF + (1.0f - DECAYF) * es.x) * inv;
    o.y = (ea.y * DECAYF + (1.0f - DECAYF) * es.y) * inv;
    o.z = (ea.z * DECAYF + (1.0f - DECAYF) * es.z) * inv;
    o.w = (ea.w * DECAYF + (1.0f - DECAYF) * es.w) * inv;
    ((float4*)out_norm)[idx] = o;
}

extern "C" void kernel_launch(void* const* d_in, const int* in_sizes, int n_in,
                              void* d_out, int out_size, void* d_ws, size_t ws_size,
                              hipStream_t stream) {
    const float* x            = (const float*)d_in[0];
    const float* embed        = (const float*)d_in[1];
    const float* cluster_size = (const float*)d_in[2];
    const float* embed_avg    = (const float*)d_in[3];

    float* out      = (float*)d_out;
    float* out_q    = out;                               // 4194304
    float* out_ind  = out + 4194304;                     // 32768
    float* out_loss = out_ind + 32768;                   // 1
    float* out_cs   = out_loss + 1;                      // 4096
    float* out_norm = out_cs + 4096;                     // 524288

    // workspace layout (bytes)
    char* ws = (char*)d_ws;
    _Float16* estg = (_Float16*)ws;                      // 2,097,152
    float* e2h   = (float*)(ws + 2097152);               // 16,384
    int*   ind   = (int*)(ws + 2113536);                 // 131,072
    int*   offsets = (int*)(ws + 2244608);               // 16,384
    int*   cursor  = (int*)(ws + 2260992);               // 16,384
    int*   rowids  = (int*)(ws + 2277376);               // 131,072
    int*   codesorted = (int*)(ws + 2408448);            // 131,072
    float* loss  = (float*)(ws + 2539520);               // 4 (pad to 256)
    float* ntot  = loss + 1;
    int*   bins  = (int*)(ws + 2539776);                 // 16,384
    float* esum  = (float*)(ws + 2556160);               // 2,097,152
    int*   zmisc = (int*)(ws + 2539520);                 // loss/pad + bins = 16,640 B

    // zeroing of loss/bins/esum is folded into esplit_kernel (saves a dispatch)
    esplit_kernel<<<KCODES / 4, 256, 0, stream>>>(embed, estg, e2h,
                                                  (float2*)esum, zmisc);
    argmax_kernel<<<NROWS / 128, 512, 0, stream>>>(x, estg, e2h, ind, out_ind,
                                                   bins, loss);
    scan_kernel<<<1, 1024, 0, stream>>>(bins, cluster_size, loss, offsets, cursor,
                                        out_cs, ntot, out_loss);
    reorder_kernel<<<NROWS / 256, 256, 0, stream>>>(ind, cursor, rowids, codesorted);
    segred_kernel<<<NROWS / WROWS / 4, 256, 0, stream>>>(x, embed, rowids, codesorted,
                                                         offsets, bins, esum, out_q);
    norm_kernel<<<KCODES * DIM / 4 / 256, 256, 0, stream>>>(esum, embed_avg, out_cs,
                                                            ntot, out_norm);
}